// Round 1
// baseline (976.732 us; speedup 1.0000x reference)
//
#include <hip/hip_runtime.h>
#include <hip/hip_bf16.h>
#include <math.h>

// Problem constants (reference: B=1, S=2048, H=2048, E=16, I=768, top-4, shared I=768)
#define NT 2048   // tokens
#define NH 2048   // hidden
#define NE 16     // routed experts
#define NI 768    // expert intermediate (= shared intermediate)
#define NK 4      // top-k

typedef __bf16 bf16_t;
typedef __attribute__((ext_vector_type(8))) __bf16 bf16x8;
typedef __attribute__((ext_vector_type(4))) float f32x4;

__device__ __forceinline__ f32x4 mfma16x16x32(bf16x8 a, bf16x8 b, f32x4 c) {
  return __builtin_amdgcn_mfma_f32_16x16x32_bf16(a, b, c, 0, 0, 0);
}

__device__ __forceinline__ bf16x8 load8cvt(const bf16_t* p) {
  return *(const bf16x8*)p;
}
__device__ __forceinline__ bf16x8 load8cvt(const float* p) {
  float4 a = *(const float4*)p;
  float4 b = *(const float4*)(p + 4);
  bf16x8 o;
  o[0] = (bf16_t)a.x; o[1] = (bf16_t)a.y; o[2] = (bf16_t)a.z; o[3] = (bf16_t)a.w;
  o[4] = (bf16_t)b.x; o[5] = (bf16_t)b.y; o[6] = (bf16_t)b.z; o[7] = (bf16_t)b.w;
  return o;
}

// ---------------- fp32 -> bf16 conversion ----------------
__global__ __launch_bounds__(256) void k_cvt(const float* __restrict__ src,
                                             bf16_t* __restrict__ dst, long n) {
  long i = ((long)blockIdx.x * blockDim.x + threadIdx.x) * 8;
  long stride = (long)gridDim.x * blockDim.x * 8;
  for (; i < n; i += stride) {
    *(bf16x8*)(dst + i) = load8cvt(src + i);
  }
}

// ---------------- router: sigmoid + biased top-4 ----------------
__global__ __launch_bounds__(64) void k_router(const float* __restrict__ x,
                                               const float* __restrict__ rw,
                                               const float* __restrict__ eb,
                                               int* __restrict__ tki,
                                               float* __restrict__ tkw,
                                               int* __restrict__ cnt) {
  int t = blockIdx.x;
  int lane = threadIdx.x;
  const float* xr = x + (long)t * NH;
  float acc[NE];
#pragma unroll
  for (int e = 0; e < NE; ++e) acc[e] = 0.f;
  for (int it = 0; it < NH / 256; ++it) {
    int h = it * 256 + lane * 4;
    float4 xv = *(const float4*)(xr + h);
#pragma unroll
    for (int e = 0; e < NE; ++e) {
      float4 wv = *(const float4*)(rw + (long)e * NH + h);
      acc[e] += xv.x * wv.x + xv.y * wv.y + xv.z * wv.z + xv.w * wv.w;
    }
  }
#pragma unroll
  for (int e = 0; e < NE; ++e) {
    float v = acc[e];
#pragma unroll
    for (int off = 32; off > 0; off >>= 1) v += __shfl_down(v, off);
    acc[e] = v;
  }
  if (lane == 0) {
    float s[NE], b[NE];
#pragma unroll
    for (int e = 0; e < NE; ++e) {
      s[e] = 1.f / (1.f + __expf(-acc[e]));
      b[e] = s[e] + eb[e];
    }
    int sel[NK];
    float ssum = 0.f;
    unsigned used = 0;
    for (int kk = 0; kk < NK; ++kk) {
      int best = 0;
      float bv = -1e30f;
      for (int e = 0; e < NE; ++e)
        if (!((used >> e) & 1u) && b[e] > bv) { bv = b[e]; best = e; }
      used |= 1u << best;
      sel[kk] = best;
      ssum += s[best];
    }
    float inv = 1.f / (ssum + 1e-20f);
    for (int kk = 0; kk < NK; ++kk) {
      tki[t * NK + kk] = sel[kk];
      tkw[t * NK + kk] = s[sel[kk]] * inv;
      atomicAdd(cnt + sel[kk], 1);
    }
  }
}

// ---------------- exclusive scan over 16 expert counts ----------------
__global__ void k_scan(const int* __restrict__ cnt, int* __restrict__ offs) {
  if (threadIdx.x == 0) {
    int o = 0;
    for (int e = 0; e < NE; ++e) { offs[e] = o; o += cnt[e]; }
    offs[NE] = o;
  }
}

// ---------------- fill compact slot lists ----------------
__global__ __launch_bounds__(256) void k_fill(const int* __restrict__ tki,
                                              const int* __restrict__ offs,
                                              int* __restrict__ cnt2,
                                              int* __restrict__ tos,
                                              int* __restrict__ sot) {
  int t = blockIdx.x * blockDim.x + threadIdx.x;
  if (t >= NT) return;
#pragma unroll
  for (int kk = 0; kk < NK; ++kk) {
    int e = tki[t * NK + kk];
    int pos = atomicAdd(cnt2 + e, 1);
    int slot = offs[e] + pos;
    tos[slot] = t;
    sot[t * NK + kk] = slot;
  }
}

// ---------------- gate-up GEMM + SwiGLU epilogue ----------------
// grid: (16 Mtiles, 6 Ntiles, 17 groups). group<16: routed expert; group 16: shared.
// act[slot][NI]: routed slots [0,4T), shared rows [4T,5T).
template <typename WT>
__global__ __launch_bounds__(256, 2) void k_gateup(
    const bf16_t* __restrict__ xb, const WT* __restrict__ gup,
    const WT* __restrict__ sg, const WT* __restrict__ su,
    const int* __restrict__ cnt, const int* __restrict__ offs,
    const int* __restrict__ tos, bf16_t* __restrict__ act) {
  constexpr int LDA = 40;  // padded LDS stride (bf16 elems); 80B keeps 16B-aligned b128 reads
  __shared__ __align__(16) bf16_t As[128 * LDA];
  __shared__ __align__(16) bf16_t Bg[128 * LDA];
  __shared__ __align__(16) bf16_t Bu[128 * LDA];
  int g = blockIdx.z, tm = blockIdx.x, tn = blockIdx.y;
  int cntE, slotbase;
  const WT *gp, *up;
  if (g < NE) {
    cntE = cnt[g];
    slotbase = offs[g];
    gp = gup + (size_t)g * 2 * NI * NH;
    up = gp + (size_t)NI * NH;
  } else {
    cntE = NT;
    slotbase = NK * NT;
    gp = sg;
    up = su;
  }
  int m0 = tm * 128;
  if (m0 >= cntE) return;
  int n0 = tn * 128;
  int tid = threadIdx.x;

  // A staging map: 128 rows x 4 chunks(8 bf16) = 512 tasks, 2/thread (gathered rows)
  const bf16_t* a_src[2];
  int a_dst[2];
#pragma unroll
  for (int i = 0; i < 2; ++i) {
    int task = tid + i * 256;
    int row = task >> 2, ch = task & 3;
    int tok = 0;
    if (g < NE) {
      if (m0 + row < cntE) tok = tos[slotbase + m0 + row];
    } else {
      tok = m0 + row;
    }
    a_src[i] = xb + (size_t)tok * NH + ch * 8;
    a_dst[i] = row * LDA + ch * 8;
  }
  // B staging: 2 matrices x 128 rows x 4 chunks = 1024 tasks, 4/thread
  const WT* b_src[4];
  bf16_t* b_dst[4];
#pragma unroll
  for (int i = 0; i < 4; ++i) {
    int task = tid + i * 256;
    int mat = task >> 9, row = (task >> 2) & 127, ch = task & 3;
    b_src[i] = (mat ? up : gp) + (size_t)(n0 + row) * NH + ch * 8;
    b_dst[i] = (mat ? Bu : Bg) + row * LDA + ch * 8;
  }

  f32x4 zero = {0.f, 0.f, 0.f, 0.f};
  f32x4 accg[4][4], accu[4][4];
#pragma unroll
  for (int mi = 0; mi < 4; ++mi)
#pragma unroll
    for (int ni = 0; ni < 4; ++ni) {
      accg[mi][ni] = zero;
      accu[mi][ni] = zero;
    }
  int wave = tid >> 6, lane = tid & 63;
  int wm = (wave >> 1) * 64, wn = (wave & 1) * 64;
  int lm = lane & 15, lq = lane >> 4;

  for (int kt = 0; kt < NH / 32; ++kt) {
    if (kt) __syncthreads();
    int koff = kt * 32;
#pragma unroll
    for (int i = 0; i < 2; ++i)
      *(bf16x8*)(As + a_dst[i]) = load8cvt(a_src[i] + koff);
#pragma unroll
    for (int i = 0; i < 4; ++i)
      *(bf16x8*)b_dst[i] = load8cvt(b_src[i] + koff);
    __syncthreads();
    bf16x8 af[4], bg[4], bu[4];
#pragma unroll
    for (int mi = 0; mi < 4; ++mi)
      af[mi] = *(const bf16x8*)(As + (wm + mi * 16 + lm) * LDA + lq * 8);
#pragma unroll
    for (int ni = 0; ni < 4; ++ni) {
      bg[ni] = *(const bf16x8*)(Bg + (wn + ni * 16 + lm) * LDA + lq * 8);
      bu[ni] = *(const bf16x8*)(Bu + (wn + ni * 16 + lm) * LDA + lq * 8);
    }
#pragma unroll
    for (int mi = 0; mi < 4; ++mi)
#pragma unroll
      for (int ni = 0; ni < 4; ++ni) {
        accg[mi][ni] = mfma16x16x32(af[mi], bg[ni], accg[mi][ni]);
        accu[mi][ni] = mfma16x16x32(af[mi], bu[ni], accu[mi][ni]);
      }
  }
  // SwiGLU epilogue: act = silu(g) * u   (C/D layout: col=lane&15, row=quad*4+reg)
#pragma unroll
  for (int mi = 0; mi < 4; ++mi) {
#pragma unroll
    for (int r = 0; r < 4; ++r) {
      int row = wm + mi * 16 + lq * 4 + r;
      if (m0 + row >= cntE) continue;
      size_t obase = (size_t)(slotbase + m0 + row) * NI + n0 + wn;
#pragma unroll
      for (int ni = 0; ni < 4; ++ni) {
        float gv = accg[mi][ni][r];
        float uv = accu[mi][ni][r];
        float a = gv / (1.f + __expf(-gv)) * uv;
        act[obase + ni * 16 + lm] = (bf16_t)a;
      }
    }
  }
}

// ---------------- down GEMM ----------------
// grid: (16 Mtiles, 16 Ntiles, 17 groups). Writes dout[slot][NH] (bf16), unweighted.
template <typename WT>
__global__ __launch_bounds__(256, 2) void k_down(
    const bf16_t* __restrict__ act, const WT* __restrict__ dwn,
    const WT* __restrict__ sd, const int* __restrict__ cnt,
    const int* __restrict__ offs, bf16_t* __restrict__ dout) {
  constexpr int LDA = 40;
  __shared__ __align__(16) bf16_t As[128 * LDA];
  __shared__ __align__(16) bf16_t Bs[128 * LDA];
  int g = blockIdx.z, tm = blockIdx.x, tn = blockIdx.y;
  int cntE, slotbase;
  const WT* wp;
  if (g < NE) {
    cntE = cnt[g];
    slotbase = offs[g];
    wp = dwn + (size_t)g * NH * NI;
  } else {
    cntE = NT;
    slotbase = NK * NT;
    wp = sd;
  }
  int m0 = tm * 128;
  if (m0 >= cntE) return;
  int n0 = tn * 128;
  int tid = threadIdx.x;

  const bf16_t* a_src[2];
  int a_dst[2];
  const WT* b_src[2];
  int b_dst[2];
#pragma unroll
  for (int i = 0; i < 2; ++i) {
    int task = tid + i * 256;
    int row = task >> 2, ch = task & 3;
    a_src[i] = act + (size_t)(slotbase + m0 + row) * NI + ch * 8;
    a_dst[i] = row * LDA + ch * 8;
    b_src[i] = wp + (size_t)(n0 + row) * NI + ch * 8;
    b_dst[i] = row * LDA + ch * 8;
  }
  f32x4 zero = {0.f, 0.f, 0.f, 0.f};
  f32x4 acc[4][4];
#pragma unroll
  for (int mi = 0; mi < 4; ++mi)
#pragma unroll
    for (int ni = 0; ni < 4; ++ni) acc[mi][ni] = zero;
  int wave = tid >> 6, lane = tid & 63;
  int wm = (wave >> 1) * 64, wn = (wave & 1) * 64;
  int lm = lane & 15, lq = lane >> 4;

  for (int kt = 0; kt < NI / 32; ++kt) {
    if (kt) __syncthreads();
    int koff = kt * 32;
#pragma unroll
    for (int i = 0; i < 2; ++i)
      *(bf16x8*)(As + a_dst[i]) = load8cvt(a_src[i] + koff);
#pragma unroll
    for (int i = 0; i < 2; ++i)
      *(bf16x8*)(Bs + b_dst[i]) = load8cvt(b_src[i] + koff);
    __syncthreads();
    bf16x8 af[4], bf[4];
#pragma unroll
    for (int mi = 0; mi < 4; ++mi)
      af[mi] = *(const bf16x8*)(As + (wm + mi * 16 + lm) * LDA + lq * 8);
#pragma unroll
    for (int ni = 0; ni < 4; ++ni)
      bf[ni] = *(const bf16x8*)(Bs + (wn + ni * 16 + lm) * LDA + lq * 8);
#pragma unroll
    for (int mi = 0; mi < 4; ++mi)
#pragma unroll
      for (int ni = 0; ni < 4; ++ni)
        acc[mi][ni] = mfma16x16x32(af[mi], bf[ni], acc[mi][ni]);
  }
#pragma unroll
  for (int mi = 0; mi < 4; ++mi) {
#pragma unroll
    for (int r = 0; r < 4; ++r) {
      int row = wm + mi * 16 + lq * 4 + r;
      if (m0 + row >= cntE) continue;
      size_t obase = (size_t)(slotbase + m0 + row) * NH + n0 + wn;
#pragma unroll
      for (int ni = 0; ni < 4; ++ni)
        dout[obase + ni * 16 + lm] = (bf16_t)acc[mi][ni][r];
    }
  }
}

// ---------------- combine: weighted sum of 4 routed slots + shared ----------------
__global__ __launch_bounds__(256) void k_combine(const bf16_t* __restrict__ dout,
                                                 const int* __restrict__ sot,
                                                 const float* __restrict__ tkw,
                                                 float* __restrict__ out) {
  int t = blockIdx.x;
  int h0 = threadIdx.x * 8;
  int s0 = sot[t * 4 + 0], s1 = sot[t * 4 + 1], s2 = sot[t * 4 + 2], s3 = sot[t * 4 + 3];
  float w0 = tkw[t * 4 + 0], w1 = tkw[t * 4 + 1], w2 = tkw[t * 4 + 2], w3 = tkw[t * 4 + 3];
  bf16x8 v0 = *(const bf16x8*)(dout + (size_t)s0 * NH + h0);
  bf16x8 v1 = *(const bf16x8*)(dout + (size_t)s1 * NH + h0);
  bf16x8 v2 = *(const bf16x8*)(dout + (size_t)s2 * NH + h0);
  bf16x8 v3 = *(const bf16x8*)(dout + (size_t)s3 * NH + h0);
  bf16x8 vs = *(const bf16x8*)(dout + (size_t)(NK * NT + t) * NH + h0);
  float o[8];
#pragma unroll
  for (int j = 0; j < 8; ++j)
    o[j] = w0 * (float)v0[j] + w1 * (float)v1[j] + w2 * (float)v2[j] +
           w3 * (float)v3[j] + (float)vs[j];
  float* op = out + (size_t)t * NH + h0;
  *(float4*)op = make_float4(o[0], o[1], o[2], o[3]);
  *(float4*)(op + 4) = make_float4(o[4], o[5], o[6], o[7]);
}

// ---------------- host launcher ----------------
extern "C" void kernel_launch(void* const* d_in, const int* in_sizes, int n_in,
                              void* d_out, int out_size, void* d_ws, size_t ws_size,
                              hipStream_t stream) {
  const float* x   = (const float*)d_in[0];
  const float* rw  = (const float*)d_in[1];
  const float* eb  = (const float*)d_in[2];
  const float* gup = (const float*)d_in[3];
  const float* dwn = (const float*)d_in[4];
  const float* sg  = (const float*)d_in[5];
  const float* su  = (const float*)d_in[6];
  const float* sd  = (const float*)d_in[7];
  float* out = (float*)d_out;

  char* ws = (char*)d_ws;
  size_t off = 0;
  auto alloc = [&](size_t b) {
    size_t p = off;
    off = (off + b + 255) & ~(size_t)255;
    return p;
  };
  int*    cnt  = (int*)(ws + alloc(NE * 4));
  int*    cnt2 = (int*)(ws + alloc(NE * 4));
  int*    offs = (int*)(ws + alloc((NE + 1) * 4));
  int*    tki  = (int*)(ws + alloc((size_t)NT * NK * 4));
  float*  tkw  = (float*)(ws + alloc((size_t)NT * NK * 4));
  int*    tos  = (int*)(ws + alloc((size_t)NK * NT * 4));
  int*    sot  = (int*)(ws + alloc((size_t)NT * NK * 4));
  bf16_t* xb   = (bf16_t*)(ws + alloc((size_t)NT * NH * 2));
  bf16_t* act  = (bf16_t*)(ws + alloc((size_t)(NK + 1) * NT * NI * 2));
  bf16_t* dob  = (bf16_t*)(ws + alloc((size_t)(NK + 1) * NT * NH * 2));

  const size_t n_gup = (size_t)NE * 2 * NI * NH;
  const size_t n_dwn = (size_t)NE * NH * NI;
  const size_t n_sw  = (size_t)NI * NH;
  bool tierA = (off + (n_gup + n_dwn + 3 * n_sw) * 2 + 2048) <= ws_size;
  bf16_t *gupb = nullptr, *dwnb = nullptr, *sgb = nullptr, *sub = nullptr, *sdb = nullptr;
  if (tierA) {
    gupb = (bf16_t*)(ws + alloc(n_gup * 2));
    dwnb = (bf16_t*)(ws + alloc(n_dwn * 2));
    sgb  = (bf16_t*)(ws + alloc(n_sw * 2));
    sub  = (bf16_t*)(ws + alloc(n_sw * 2));
    sdb  = (bf16_t*)(ws + alloc(n_sw * 2));
  }

  hipMemsetAsync(cnt, 0, NE * 4, stream);
  hipMemsetAsync(cnt2, 0, NE * 4, stream);

  auto cvt = [&](const float* s, bf16_t* d, size_t n) {
    int blocks = (int)((n / 8 + 255) / 256);
    k_cvt<<<blocks, 256, 0, stream>>>(s, d, (long)n);
  };
  cvt(x, xb, (size_t)NT * NH);
  if (tierA) {
    cvt(gup, gupb, n_gup);
    cvt(dwn, dwnb, n_dwn);
    cvt(sg, sgb, n_sw);
    cvt(su, sub, n_sw);
    cvt(sd, sdb, n_sw);
  }

  k_router<<<NT, 64, 0, stream>>>(x, rw, eb, tki, tkw, cnt);
  k_scan<<<1, 64, 0, stream>>>(cnt, offs);
  k_fill<<<NT / 256, 256, 0, stream>>>(tki, offs, cnt2, tos, sot);

  dim3 gu_grid(16, NI / 128, NE + 1);
  dim3 dn_grid(16, NH / 128, NE + 1);
  if (tierA) {
    k_gateup<bf16_t><<<gu_grid, 256, 0, stream>>>(xb, gupb, sgb, sub, cnt, offs, tos, act);
    k_down<bf16_t><<<dn_grid, 256, 0, stream>>>(act, dwnb, sdb, cnt, offs, dob);
  } else {
    k_gateup<float><<<gu_grid, 256, 0, stream>>>(xb, gup, sg, su, cnt, offs, tos, act);
    k_down<float><<<dn_grid, 256, 0, stream>>>(act, dwn, sd, cnt, offs, dob);
  }

  k_combine<<<NT, 256, 0, stream>>>(dob, sot, tkw, out);
}

// Round 2
// 927.329 us; speedup vs baseline: 1.0533x; 1.0533x over previous
//
#include <hip/hip_runtime.h>
#include <hip/hip_bf16.h>
#include <math.h>
#include <type_traits>

// Problem constants (reference: B=1, S=2048, H=2048, E=16, I=768, top-4, shared I=768)
#define NT 2048   // tokens
#define NH 2048   // hidden
#define NE 16     // routed experts
#define NI 768    // expert intermediate (= shared intermediate)
#define NK 4      // top-k

typedef __bf16 bf16_t;
typedef __attribute__((ext_vector_type(8))) __bf16 bf16x8;
typedef __attribute__((ext_vector_type(4))) __bf16 bf16x4;
typedef __attribute__((ext_vector_type(4))) float f32x4;

__device__ __forceinline__ f32x4 mfma16x16x32(bf16x8 a, bf16x8 b, f32x4 c) {
  return __builtin_amdgcn_mfma_f32_16x16x32_bf16(a, b, c, 0, 0, 0);
}

// async global->LDS DMA, 16B per lane; LDS dest = wave-uniform base + lane*16
__device__ __forceinline__ void async16(const bf16_t* g, bf16_t* l) {
  __builtin_amdgcn_global_load_lds(
      (const __attribute__((address_space(1))) void*)g,
      (__attribute__((address_space(3))) void*)l, 16, 0, 0);
}

__device__ __forceinline__ bf16x8 load8cvt(const bf16_t* p) {
  return *(const bf16x8*)p;
}
__device__ __forceinline__ bf16x8 load8cvt(const float* p) {
  float4 a = *(const float4*)p;
  float4 b = *(const float4*)(p + 4);
  bf16x8 o;
  o[0] = (bf16_t)a.x; o[1] = (bf16_t)a.y; o[2] = (bf16_t)a.z; o[3] = (bf16_t)a.w;
  o[4] = (bf16_t)b.x; o[5] = (bf16_t)b.y; o[6] = (bf16_t)b.z; o[7] = (bf16_t)b.w;
  return o;
}

// ---------------- fp32 -> bf16 conversion (weights) ----------------
__global__ __launch_bounds__(256) void k_cvt(const float* __restrict__ src,
                                             bf16_t* __restrict__ dst, long n) {
  long i = ((long)blockIdx.x * blockDim.x + threadIdx.x) * 8;
  long stride = (long)gridDim.x * blockDim.x * 8;
  for (; i < n; i += stride) {
    *(bf16x8*)(dst + i) = load8cvt(src + i);
  }
}

// ---------------- router: sigmoid + biased top-4 (+ fused x->bf16 cvt) ----------------
__global__ __launch_bounds__(64) void k_router(const float* __restrict__ x,
                                               const float* __restrict__ rw,
                                               const float* __restrict__ eb,
                                               int* __restrict__ tki,
                                               float* __restrict__ tkw,
                                               int* __restrict__ cnt,
                                               bf16_t* __restrict__ xb) {
  int t = blockIdx.x;
  int lane = threadIdx.x;
  const float* xr = x + (long)t * NH;
  float acc[NE];
#pragma unroll
  for (int e = 0; e < NE; ++e) acc[e] = 0.f;
  for (int it = 0; it < NH / 256; ++it) {
    int h = it * 256 + lane * 4;
    float4 xv = *(const float4*)(xr + h);
    bf16x4 xc;
    xc[0] = (bf16_t)xv.x; xc[1] = (bf16_t)xv.y; xc[2] = (bf16_t)xv.z; xc[3] = (bf16_t)xv.w;
    *(bf16x4*)(xb + (size_t)t * NH + h) = xc;
#pragma unroll
    for (int e = 0; e < NE; ++e) {
      float4 wv = *(const float4*)(rw + (long)e * NH + h);
      acc[e] += xv.x * wv.x + xv.y * wv.y + xv.z * wv.z + xv.w * wv.w;
    }
  }
#pragma unroll
  for (int e = 0; e < NE; ++e) {
    float v = acc[e];
#pragma unroll
    for (int off = 32; off > 0; off >>= 1) v += __shfl_down(v, off);
    acc[e] = v;
  }
  if (lane == 0) {
    float s[NE], b[NE];
#pragma unroll
    for (int e = 0; e < NE; ++e) {
      s[e] = 1.f / (1.f + __expf(-acc[e]));
      b[e] = s[e] + eb[e];
    }
    int sel[NK];
    float ssum = 0.f;
    unsigned used = 0;
    for (int kk = 0; kk < NK; ++kk) {
      int best = 0;
      float bv = -1e30f;
      for (int e = 0; e < NE; ++e)
        if (!((used >> e) & 1u) && b[e] > bv) { bv = b[e]; best = e; }
      used |= 1u << best;
      sel[kk] = best;
      ssum += s[best];
    }
    float inv = 1.f / (ssum + 1e-20f);
    for (int kk = 0; kk < NK; ++kk) {
      tki[t * NK + kk] = sel[kk];
      tkw[t * NK + kk] = s[sel[kk]] * inv;
      atomicAdd(cnt + sel[kk], 1);
    }
  }
}

// ---------------- exclusive scan over 16 expert counts ----------------
__global__ void k_scan(const int* __restrict__ cnt, int* __restrict__ offs) {
  if (threadIdx.x == 0) {
    int o = 0;
    for (int e = 0; e < NE; ++e) { offs[e] = o; o += cnt[e]; }
    offs[NE] = o;
  }
}

// ---------------- fill compact slot lists ----------------
__global__ __launch_bounds__(256) void k_fill(const int* __restrict__ tki,
                                              const int* __restrict__ offs,
                                              int* __restrict__ cnt2,
                                              int* __restrict__ tos,
                                              int* __restrict__ sot) {
  int t = blockIdx.x * blockDim.x + threadIdx.x;
  if (t >= NT) return;
#pragma unroll
  for (int kk = 0; kk < NK; ++kk) {
    int e = tki[t * NK + kk];
    int pos = atomicAdd(cnt2 + e, 1);
    int slot = offs[e] + pos;
    tos[slot] = t;
    sot[t * NK + kk] = slot;
  }
}

// LDS tile layout (unpadded, required by global_load_lds lane-order writes):
//   row r (0..127), chunk slot c (0..3, 8 bf16 each): offset r*32 + c*8 elems.
//   Source chunk stored at slot c is cg = c ^ ((r>>1)&3)  (XOR swizzle -> <=2-way
//   bank aliasing on fragment ds_read_b128, which is free per m136).
//   Staging lane l of a 16-row wave-issue: row rb+(l>>2), slot l&3,
//   source chunk cg = (l&3) ^ ((l>>3)&3)  (independent of rb since rb%16==0).
//   Fragment read of k-chunk lq, row lm (local): slot = lq ^ ((lm>>1)&3).

// ---------------- gate-up GEMM + SwiGLU epilogue ----------------
// grid: (16 Mtiles, 6 Ntiles, 17 groups). group<16: routed expert; group 16: shared.
// act[slot][NI]: routed slots [0,4T), shared rows [4T,5T).
template <typename WT>
__global__ __launch_bounds__(256, 2) void k_gateup(
    const bf16_t* __restrict__ xb, const WT* __restrict__ gup,
    const WT* __restrict__ sg, const WT* __restrict__ su,
    const int* __restrict__ cnt, const int* __restrict__ offs,
    const int* __restrict__ tos, bf16_t* __restrict__ act) {
  __shared__ __align__(16) bf16_t As[128 * 32];
  __shared__ __align__(16) bf16_t Bg[128 * 32];
  __shared__ __align__(16) bf16_t Bu[128 * 32];
  int g = blockIdx.z, tm = blockIdx.x, tn = blockIdx.y;
  int cntE, slotbase;
  const WT *gp, *up;
  if (g < NE) {
    cntE = cnt[g];
    slotbase = offs[g];
    gp = gup + (size_t)g * 2 * NI * NH;
    up = gp + (size_t)NI * NH;
  } else {
    cntE = NT;
    slotbase = NK * NT;
    gp = sg;
    up = su;
  }
  int m0 = tm * 128;
  if (m0 >= cntE) return;
  int n0 = tn * 128;
  int tid = threadIdx.x;
  int wave = tid >> 6, lane = tid & 63;
  int lrow = lane >> 2;                       // 0..15 in a 16-row issue
  int cg = (lane & 3) ^ ((lane >> 3) & 3);    // swizzled source chunk

  // A staging: 8 wave-issues of 16 rows; wave w handles issues 2w, 2w+1.
  const bf16_t* a_g[2];
  bf16_t* a_l[2];
#pragma unroll
  for (int j = 0; j < 2; ++j) {
    int rb = (wave * 2 + j) * 16;
    int r = rb + lrow;
    int tok;
    if (g < NE)
      tok = (m0 + r < cntE) ? tos[slotbase + m0 + r] : 0;
    else
      tok = m0 + r;
    a_g[j] = xb + (size_t)tok * NH + cg * 8;
    a_l[j] = As + rb * 32;
  }
  // B staging: 2 matrices x 8 issues = 16; wave w handles issues 4w..4w+3.
  const WT* b_g[4];
  bf16_t* b_l[4];
#pragma unroll
  for (int j = 0; j < 4; ++j) {
    int idx = wave * 4 + j;
    int mat = idx >> 3;
    int rb = (idx & 7) * 16;
    int r = rb + lrow;
    b_g[j] = (mat ? up : gp) + (size_t)(n0 + r) * NH + cg * 8;
    b_l[j] = (mat ? Bu : Bg) + rb * 32;
  }

  f32x4 zero = {0.f, 0.f, 0.f, 0.f};
  f32x4 accg[4][4], accu[4][4];
#pragma unroll
  for (int mi = 0; mi < 4; ++mi)
#pragma unroll
    for (int ni = 0; ni < 4; ++ni) {
      accg[mi][ni] = zero;
      accu[mi][ni] = zero;
    }
  int wm = (wave >> 1) * 64, wn = (wave & 1) * 64;
  int lm = lane & 15, lq = lane >> 4;
  int slot8 = (lq ^ ((lm >> 1) & 3)) * 8;     // fragment-read chunk slot

  for (int kt = 0; kt < NH / 32; ++kt) {
    if (kt) __syncthreads();
    int koff = kt * 32;
#pragma unroll
    for (int j = 0; j < 2; ++j) async16(a_g[j] + koff, a_l[j]);
    if constexpr (std::is_same<WT, bf16_t>::value) {
#pragma unroll
      for (int j = 0; j < 4; ++j) async16(b_g[j] + koff, b_l[j]);
    } else {
#pragma unroll
      for (int j = 0; j < 4; ++j)
        *(bf16x8*)(b_l[j] + lane * 8) = load8cvt(b_g[j] + koff);
    }
    __syncthreads();
    bf16x8 af[4], bg[4], bu[4];
#pragma unroll
    for (int mi = 0; mi < 4; ++mi)
      af[mi] = *(const bf16x8*)(As + (wm + mi * 16 + lm) * 32 + slot8);
#pragma unroll
    for (int ni = 0; ni < 4; ++ni) {
      bg[ni] = *(const bf16x8*)(Bg + (wn + ni * 16 + lm) * 32 + slot8);
      bu[ni] = *(const bf16x8*)(Bu + (wn + ni * 16 + lm) * 32 + slot8);
    }
#pragma unroll
    for (int mi = 0; mi < 4; ++mi)
#pragma unroll
      for (int ni = 0; ni < 4; ++ni) {
        accg[mi][ni] = mfma16x16x32(af[mi], bg[ni], accg[mi][ni]);
        accu[mi][ni] = mfma16x16x32(af[mi], bu[ni], accu[mi][ni]);
      }
  }
  // SwiGLU epilogue: act = silu(g) * u   (C/D layout: col=lane&15, row=quad*4+reg)
#pragma unroll
  for (int mi = 0; mi < 4; ++mi) {
#pragma unroll
    for (int r = 0; r < 4; ++r) {
      int row = wm + mi * 16 + lq * 4 + r;
      if (m0 + row >= cntE) continue;
      size_t obase = (size_t)(slotbase + m0 + row) * NI + n0 + wn;
#pragma unroll
      for (int ni = 0; ni < 4; ++ni) {
        float gv = accg[mi][ni][r];
        float uv = accu[mi][ni][r];
        float a = gv / (1.f + __expf(-gv)) * uv;
        act[obase + ni * 16 + lm] = (bf16_t)a;
      }
    }
  }
}

// ---------------- down GEMM ----------------
// grid: (16 Mtiles, 16 Ntiles, 17 groups). Writes dout[slot][NH] (bf16), unweighted.
template <typename WT>
__global__ __launch_bounds__(256, 2) void k_down(
    const bf16_t* __restrict__ act, const WT* __restrict__ dwn,
    const WT* __restrict__ sd, const int* __restrict__ cnt,
    const int* __restrict__ offs, bf16_t* __restrict__ dout) {
  __shared__ __align__(16) bf16_t As[128 * 32];
  __shared__ __align__(16) bf16_t Bs[128 * 32];
  int g = blockIdx.z, tm = blockIdx.x, tn = blockIdx.y;
  int cntE, slotbase;
  const WT* wp;
  if (g < NE) {
    cntE = cnt[g];
    slotbase = offs[g];
    wp = dwn + (size_t)g * NH * NI;
  } else {
    cntE = NT;
    slotbase = NK * NT;
    wp = sd;
  }
  int m0 = tm * 128;
  if (m0 >= cntE) return;
  int n0 = tn * 128;
  int tid = threadIdx.x;
  int wave = tid >> 6, lane = tid & 63;
  int lrow = lane >> 2;
  int cg = (lane & 3) ^ ((lane >> 3) & 3);

  const bf16_t* a_g[2];
  bf16_t* a_l[2];
  const WT* b_g[2];
  bf16_t* b_l[2];
#pragma unroll
  for (int j = 0; j < 2; ++j) {
    int rb = (wave * 2 + j) * 16;
    int r = rb + lrow;
    a_g[j] = act + (size_t)(slotbase + m0 + r) * NI + cg * 8;
    a_l[j] = As + rb * 32;
    b_g[j] = wp + (size_t)(n0 + r) * NI + cg * 8;
    b_l[j] = Bs + rb * 32;
  }
  f32x4 zero = {0.f, 0.f, 0.f, 0.f};
  f32x4 acc[4][4];
#pragma unroll
  for (int mi = 0; mi < 4; ++mi)
#pragma unroll
    for (int ni = 0; ni < 4; ++ni) acc[mi][ni] = zero;
  int wm = (wave >> 1) * 64, wn = (wave & 1) * 64;
  int lm = lane & 15, lq = lane >> 4;
  int slot8 = (lq ^ ((lm >> 1) & 3)) * 8;

  for (int kt = 0; kt < NI / 32; ++kt) {
    if (kt) __syncthreads();
    int koff = kt * 32;
#pragma unroll
    for (int j = 0; j < 2; ++j) async16(a_g[j] + koff, a_l[j]);
    if constexpr (std::is_same<WT, bf16_t>::value) {
#pragma unroll
      for (int j = 0; j < 2; ++j) async16(b_g[j] + koff, b_l[j]);
    } else {
#pragma unroll
      for (int j = 0; j < 2; ++j)
        *(bf16x8*)(b_l[j] + lane * 8) = load8cvt(b_g[j] + koff);
    }
    __syncthreads();
    bf16x8 af[4], bf[4];
#pragma unroll
    for (int mi = 0; mi < 4; ++mi)
      af[mi] = *(const bf16x8*)(As + (wm + mi * 16 + lm) * 32 + slot8);
#pragma unroll
    for (int ni = 0; ni < 4; ++ni)
      bf[ni] = *(const bf16x8*)(Bs + (wn + ni * 16 + lm) * 32 + slot8);
#pragma unroll
    for (int mi = 0; mi < 4; ++mi)
#pragma unroll
      for (int ni = 0; ni < 4; ++ni)
        acc[mi][ni] = mfma16x16x32(af[mi], bf[ni], acc[mi][ni]);
  }
#pragma unroll
  for (int mi = 0; mi < 4; ++mi) {
#pragma unroll
    for (int r = 0; r < 4; ++r) {
      int row = wm + mi * 16 + lq * 4 + r;
      if (m0 + row >= cntE) continue;
      size_t obase = (size_t)(slotbase + m0 + row) * NH + n0 + wn;
#pragma unroll
      for (int ni = 0; ni < 4; ++ni)
        dout[obase + ni * 16 + lm] = (bf16_t)acc[mi][ni][r];
    }
  }
}

// ---------------- combine: weighted sum of 4 routed slots + shared ----------------
__global__ __launch_bounds__(256) void k_combine(const bf16_t* __restrict__ dout,
                                                 const int* __restrict__ sot,
                                                 const float* __restrict__ tkw,
                                                 float* __restrict__ out) {
  int t = blockIdx.x;
  int h0 = threadIdx.x * 8;
  int s0 = sot[t * 4 + 0], s1 = sot[t * 4 + 1], s2 = sot[t * 4 + 2], s3 = sot[t * 4 + 3];
  float w0 = tkw[t * 4 + 0], w1 = tkw[t * 4 + 1], w2 = tkw[t * 4 + 2], w3 = tkw[t * 4 + 3];
  bf16x8 v0 = *(const bf16x8*)(dout + (size_t)s0 * NH + h0);
  bf16x8 v1 = *(const bf16x8*)(dout + (size_t)s1 * NH + h0);
  bf16x8 v2 = *(const bf16x8*)(dout + (size_t)s2 * NH + h0);
  bf16x8 v3 = *(const bf16x8*)(dout + (size_t)s3 * NH + h0);
  bf16x8 vs = *(const bf16x8*)(dout + (size_t)(NK * NT + t) * NH + h0);
  float o[8];
#pragma unroll
  for (int j = 0; j < 8; ++j)
    o[j] = w0 * (float)v0[j] + w1 * (float)v1[j] + w2 * (float)v2[j] +
           w3 * (float)v3[j] + (float)vs[j];
  float* op = out + (size_t)t * NH + h0;
  *(float4*)op = make_float4(o[0], o[1], o[2], o[3]);
  *(float4*)(op + 4) = make_float4(o[4], o[5], o[6], o[7]);
}

// ---------------- host launcher ----------------
extern "C" void kernel_launch(void* const* d_in, const int* in_sizes, int n_in,
                              void* d_out, int out_size, void* d_ws, size_t ws_size,
                              hipStream_t stream) {
  const float* x   = (const float*)d_in[0];
  const float* rw  = (const float*)d_in[1];
  const float* eb  = (const float*)d_in[2];
  const float* gup = (const float*)d_in[3];
  const float* dwn = (const float*)d_in[4];
  const float* sg  = (const float*)d_in[5];
  const float* su  = (const float*)d_in[6];
  const float* sd  = (const float*)d_in[7];
  float* out = (float*)d_out;

  char* ws = (char*)d_ws;
  size_t off = 0;
  auto alloc = [&](size_t b) {
    size_t p = off;
    off = (off + b + 255) & ~(size_t)255;
    return p;
  };
  int*    cnt  = (int*)(ws + alloc(NE * 4));
  int*    cnt2 = (int*)(ws + alloc(NE * 4));
  int*    offs = (int*)(ws + alloc((NE + 1) * 4));
  int*    tki  = (int*)(ws + alloc((size_t)NT * NK * 4));
  float*  tkw  = (float*)(ws + alloc((size_t)NT * NK * 4));
  int*    tos  = (int*)(ws + alloc((size_t)NK * NT * 4));
  int*    sot  = (int*)(ws + alloc((size_t)NT * NK * 4));
  bf16_t* xb   = (bf16_t*)(ws + alloc((size_t)NT * NH * 2));
  bf16_t* act  = (bf16_t*)(ws + alloc((size_t)(NK + 1) * NT * NI * 2));
  bf16_t* dob  = (bf16_t*)(ws + alloc((size_t)(NK + 1) * NT * NH * 2));

  const size_t n_gup = (size_t)NE * 2 * NI * NH;
  const size_t n_dwn = (size_t)NE * NH * NI;
  const size_t n_sw  = (size_t)NI * NH;
  bool tierA = (off + (n_gup + n_dwn + 3 * n_sw) * 2 + 2048) <= ws_size;
  bf16_t *gupb = nullptr, *dwnb = nullptr, *sgb = nullptr, *sub = nullptr, *sdb = nullptr;
  if (tierA) {
    gupb = (bf16_t*)(ws + alloc(n_gup * 2));
    dwnb = (bf16_t*)(ws + alloc(n_dwn * 2));
    sgb  = (bf16_t*)(ws + alloc(n_sw * 2));
    sub  = (bf16_t*)(ws + alloc(n_sw * 2));
    sdb  = (bf16_t*)(ws + alloc(n_sw * 2));
  }

  hipMemsetAsync(cnt, 0, NE * 4, stream);
  hipMemsetAsync(cnt2, 0, NE * 4, stream);

  auto cvt = [&](const float* s, bf16_t* d, size_t n) {
    int blocks = (int)((n / 8 + 255) / 256);
    k_cvt<<<blocks, 256, 0, stream>>>(s, d, (long)n);
  };
  if (tierA) {
    cvt(gup, gupb, n_gup);
    cvt(dwn, dwnb, n_dwn);
    cvt(sg, sgb, n_sw);
    cvt(su, sub, n_sw);
    cvt(sd, sdb, n_sw);
  }

  k_router<<<NT, 64, 0, stream>>>(x, rw, eb, tki, tkw, cnt, xb);
  k_scan<<<1, 64, 0, stream>>>(cnt, offs);
  k_fill<<<NT / 256, 256, 0, stream>>>(tki, offs, cnt2, tos, sot);

  dim3 gu_grid(16, NI / 128, NE + 1);
  dim3 dn_grid(16, NH / 128, NE + 1);
  if (tierA) {
    k_gateup<bf16_t><<<gu_grid, 256, 0, stream>>>(xb, gupb, sgb, sub, cnt, offs, tos, act);
    k_down<bf16_t><<<dn_grid, 256, 0, stream>>>(act, dwnb, sdb, cnt, offs, dob);
  } else {
    k_gateup<float><<<gu_grid, 256, 0, stream>>>(xb, gup, sg, su, cnt, offs, tos, act);
    k_down<float><<<dn_grid, 256, 0, stream>>>(act, dwn, sd, cnt, offs, dob);
  }

  k_combine<<<NT, 256, 0, stream>>>(dob, sot, tkw, out);
}